// Round 8
// baseline (397.177 us; speedup 1.0000x reference)
//
#include <hip/hip_runtime.h>
#include <hip/hip_bf16.h>
#include <math.h>

// Block_46643344834722: pre-norm attention block, B=512 D=2048 H=16 DH=128.
// R11: weights pass through a PURE fp32->bf16 CAST (identity layout, fully
// coalesced, one dispatch, + LN1 folded in) -- no strided transpose kernel.
// GEMM keeps R10's reg-staged LDS-transpose for B but loads bf16 [K,N]
// directly (bf16x4 row patches, no cvt): per-step streaming bytes halve,
// which was the L3-BW bottleneck (R10: 2437 cy/step at fp32 B).
// W2 drops split-K (64x64, 256 blocks, fused bias+residual) -- no partials,
// no reduce.  7 dispatches: cast+ln1, qkv, attn, wo, ln2, w1, w2.

#define DDIM 2048
#define HHEADS 16
#define DHEAD 128
#define BROWS 512
#define LN_EPS 1e-5f

typedef __bf16 bf16x8_t __attribute__((ext_vector_type(8)));
typedef __bf16 bf16x4_t __attribute__((ext_vector_type(4)));
typedef __bf16 bf16x2_t __attribute__((ext_vector_type(2)));
typedef float f32x4_t __attribute__((ext_vector_type(4)));

#define GLD16(gptr, lptr)                                                     \
    __builtin_amdgcn_global_load_lds(                                         \
        (const __attribute__((address_space(1))) void*)(gptr),                \
        (__attribute__((address_space(3))) void*)(lptr), 16, 0, 0)

// ---------------------------------------------------------------- LayerNorm
__global__ __launch_bounds__(256) void ln_kernel(const float* __restrict__ x,
                                                 const float* __restrict__ g,
                                                 const float* __restrict__ b,
                                                 __bf16* __restrict__ out) {
    const int row = blockIdx.x;
    const int tid = threadIdx.x;
    const float4* x4 = (const float4*)(x + (size_t)row * DDIM);
    float4 a = x4[2 * tid];
    float4 c = x4[2 * tid + 1];
    float s  = a.x + a.y + a.z + a.w + c.x + c.y + c.z + c.w;
    float s2 = a.x*a.x + a.y*a.y + a.z*a.z + a.w*a.w
             + c.x*c.x + c.y*c.y + c.z*c.z + c.w*c.w;
    #pragma unroll
    for (int off = 32; off > 0; off >>= 1) {
        s  += __shfl_down(s, off);
        s2 += __shfl_down(s2, off);
    }
    __shared__ float ps[4], ps2[4];
    __shared__ float mean_s, rstd_s;
    const int lane = tid & 63, w = tid >> 6;
    if (lane == 0) { ps[w] = s; ps2[w] = s2; }
    __syncthreads();
    if (tid == 0) {
        float S  = ps[0] + ps[1] + ps[2] + ps[3];
        float S2 = ps2[0] + ps2[1] + ps2[2] + ps2[3];
        float m  = S * (1.0f / DDIM);
        float var = S2 * (1.0f / DDIM) - m * m;
        mean_s = m;
        rstd_s = rsqrtf(var + LN_EPS);
    }
    __syncthreads();
    const float m = mean_s, r = rstd_s;
    const float4* g4 = (const float4*)g;
    const float4* b4 = (const float4*)b;
    float4 ga = g4[2 * tid], gb = g4[2 * tid + 1];
    float4 ba = b4[2 * tid], bb = b4[2 * tid + 1];
    bf16x8_t o;
    o[0] = (__bf16)((a.x - m) * r * ga.x + ba.x);
    o[1] = (__bf16)((a.y - m) * r * ga.y + ba.y);
    o[2] = (__bf16)((a.z - m) * r * ga.z + ba.z);
    o[3] = (__bf16)((a.w - m) * r * ga.w + ba.w);
    o[4] = (__bf16)((c.x - m) * r * gb.x + bb.x);
    o[5] = (__bf16)((c.y - m) * r * gb.y + bb.y);
    o[6] = (__bf16)((c.z - m) * r * gb.z + bb.z);
    o[7] = (__bf16)((c.w - m) * r * gb.w + bb.w);
    *(bf16x8_t*)(out + (size_t)row * DDIM + tid * 8) = o;
}

// ---------------------------------------------------------------- cast + LN1
// blocks [0,12288): identity fp32->bf16 cast of all weights into wc
//   (seg = 4M-float chunk: 0..2 Wq/Wk/Wv, 3 Wo, 4..7 W1, 8..11 W2;
//    1024 blocks x 4096 floats each; 64B read / 32B write per thread).
// blocks [12288,12800): h[row] = LN(x[row]).
__global__ __launch_bounds__(256) void cast_ln_kernel(
    const float* __restrict__ Wq, const float* __restrict__ Wk,
    const float* __restrict__ Wv, const float* __restrict__ Wo,
    const float* __restrict__ W1, const float* __restrict__ W2,
    const float* __restrict__ x, const float* __restrict__ g1,
    const float* __restrict__ be1,
    __bf16* __restrict__ wc, __bf16* __restrict__ h) {
    __shared__ float sh[32];
    const int bid = blockIdx.x;
    const int tid = threadIdx.x;
    if (bid < 12288) {
        const int seg = bid >> 10;
        const float* src;
        if (seg == 0) src = Wq;
        else if (seg == 1) src = Wk;
        else if (seg == 2) src = Wv;
        else if (seg == 3) src = Wo;
        else if (seg < 8) src = W1 + (size_t)(seg - 4) * 4194304;
        else src = W2 + (size_t)(seg - 8) * 4194304;
        __bf16* dst = wc + (size_t)seg * 4194304;
        const size_t i = (size_t)(bid & 1023) * 4096 + (size_t)tid * 16;
        const float4* s4 = (const float4*)(src + i);
        const float4 v0 = s4[0], v1 = s4[1], v2 = s4[2], v3 = s4[3];
        bf16x8_t o0, o1;
        o0[0] = (__bf16)v0.x; o0[1] = (__bf16)v0.y;
        o0[2] = (__bf16)v0.z; o0[3] = (__bf16)v0.w;
        o0[4] = (__bf16)v1.x; o0[5] = (__bf16)v1.y;
        o0[6] = (__bf16)v1.z; o0[7] = (__bf16)v1.w;
        o1[0] = (__bf16)v2.x; o1[1] = (__bf16)v2.y;
        o1[2] = (__bf16)v2.z; o1[3] = (__bf16)v2.w;
        o1[4] = (__bf16)v3.x; o1[5] = (__bf16)v3.y;
        o1[6] = (__bf16)v3.z; o1[7] = (__bf16)v3.w;
        *(bf16x8_t*)(dst + i) = o0;
        *(bf16x8_t*)(dst + i + 8) = o1;
    } else {
        const int row = bid - 12288;
        const float4* x4 = (const float4*)(x + (size_t)row * DDIM);
        float4 a = x4[2 * tid];
        float4 c = x4[2 * tid + 1];
        float s  = a.x + a.y + a.z + a.w + c.x + c.y + c.z + c.w;
        float s2 = a.x*a.x + a.y*a.y + a.z*a.z + a.w*a.w
                 + c.x*c.x + c.y*c.y + c.z*c.z + c.w*c.w;
        #pragma unroll
        for (int off = 32; off > 0; off >>= 1) {
            s  += __shfl_down(s, off);
            s2 += __shfl_down(s2, off);
        }
        const int lane = tid & 63, w = tid >> 6;
        if (lane == 0) { sh[w] = s; sh[8 + w] = s2; }
        __syncthreads();
        if (tid == 0) {
            float S  = sh[0] + sh[1] + sh[2] + sh[3];
            float S2 = sh[8] + sh[9] + sh[10] + sh[11];
            float m  = S * (1.0f / DDIM);
            float var = S2 * (1.0f / DDIM) - m * m;
            sh[16] = m;
            sh[17] = rsqrtf(var + LN_EPS);
        }
        __syncthreads();
        const float m = sh[16], r = sh[17];
        const float4* g4 = (const float4*)g1;
        const float4* b4 = (const float4*)be1;
        float4 ga = g4[2 * tid], gb = g4[2 * tid + 1];
        float4 ba = b4[2 * tid], bb = b4[2 * tid + 1];
        bf16x8_t o;
        o[0] = (__bf16)((a.x - m) * r * ga.x + ba.x);
        o[1] = (__bf16)((a.y - m) * r * ga.y + ba.y);
        o[2] = (__bf16)((a.z - m) * r * ga.z + ba.z);
        o[3] = (__bf16)((a.w - m) * r * ga.w + ba.w);
        o[4] = (__bf16)((c.x - m) * r * gb.x + bb.x);
        o[5] = (__bf16)((c.y - m) * r * gb.y + bb.y);
        o[6] = (__bf16)((c.z - m) * r * gb.z + bb.z);
        o[7] = (__bf16)((c.w - m) * r * gb.w + bb.w);
        *(bf16x8_t*)(h + (size_t)row * DDIM + tid * 8) = o;
    }
}

// ---------------------------------------------------------------- GEMM
// C[M,N] = A[M,K](bf16) @ B[K,N](bf16) + bias (+Res, relu?).
// TMxTN tile, 512 threads (8 waves: 4 wave-tiles x 2 k-halves), BK=64.
// A: global_load_lds with source k-pre-swizzle (row&7 XOR).
// B: per-thread KPERx4 bf16 row-patches -> transposed ds_write with
//    f(n)=(n^(n>>2))&7 slot-XOR (R10 geometry, cvt dropped).
// Pipeline: DEPTH=3, one barrier/K-step; issue order guarantees barrier's
// vmcnt(LB+LA) covers A(ks) and B(ks+1) (R10 invariant).
// QKV=1: B is per-head [2048,128] blocks of Wq|Wk|Wv; 3-segment bias.
template <int TM, int TN, int OUT_BF16, int RELU, int RES, int QKV>
__global__ __launch_bounds__(512, 4) void gemm_af(
    const __bf16* __restrict__ A, int K,
    const __bf16* __restrict__ Bq, const __bf16* __restrict__ Bk,
    const __bf16* __restrict__ Bv, int ldb,
    const float* __restrict__ bias, const float* __restrict__ biasB,
    const float* __restrict__ biasC, const float* __restrict__ Res,
    void* __restrict__ Cout, int N) {
    constexpr int DEPTH = 3;
    constexpr int STG = (TM + TN) * 64;  // bf16 elems per stage (BK=64)
    __shared__ __align__(16) __bf16 smem[DEPTH * STG];

    const int tid = threadIdx.x;
    const int w = tid >> 6, lane = tid & 63;

    // ---- XCD-aware block swizzle (gridDim.x % 8 == 0) ----
    const int gx = gridDim.x, gy = gridDim.y;
    int l = blockIdx.x + gx * blockIdx.y;
    const int xcd = l & 7;
    int i0 = l >> 3;
    const int by = i0 % gy; i0 /= gy;
    const int bx = xcd * (gx >> 3) + i0;

    const int m0 = by * TM, n0 = bx * TN;
    const int NK = K / 64;

    // ---- A staging (chunks of 8 rows x 64 k, one GLD16 per lane) ----
    constexpr int LA = TM / 64;
    const int srow = lane >> 3;
    const int sslot = (lane & 7) ^ srow;
    const __bf16* srcs[LA];
    int toff[LA];
    #pragma unroll
    for (int i = 0; i < LA; i++) {
        const int t = w + 8 * i;
        toff[i] = t * 512;
        srcs[i] = A + (size_t)(m0 + t * 8 + srow) * K + sslot * 8;
    }

    // ---- B staging geometry (bf16 rows) ----
    constexpr int KPER = TN / 32;  // 4 (TN=128) / 2 (TN=64)
    constexpr int LB = KPER;       // bf16x4 loads per thread per stage
    constexpr int NPR = TN / 4;
    const int np = tid & (NPR - 1);
    const int kp = tid / NPR;
    const int k0 = kp * KPER, n0t = np * 4;

    const __bf16* bbase;
    if (QKV) {
        const int seg = n0 >> 11;
        const __bf16* sel = (seg == 0) ? Bq : (seg == 1) ? Bk : Bv;
        bbase = sel + (size_t)((n0 & 2047) >> 7) * (DDIM * DHEAD);
    } else {
        bbase = Bq + n0;
    }
    const __bf16* bthr = bbase + (size_t)k0 * ldb + n0t;
    const size_t bstep = (size_t)64 * ldb;

    int bwoff[4];
    {
        const int bslot = k0 >> 3, bhalf = (k0 & 7) * 2;
        #pragma unroll
        for (int j = 0; j < 4; j++) {
            const int n = n0t + j;
            const int fb = (n ^ (n >> 2)) & 7;
            bwoff[j] = (TM + n) * 128 + ((bslot ^ fb) * 16) + bhalf;
        }
    }

    // ---- wave tiling / fragment read offsets ----
    constexpr int MI = TM / 32, NJ = TN / 32;
    const int wg = w & 3, kh = w >> 2;
    const int wm = (wg >> 1) * (TM / 2), wn = (wg & 1) * (TN / 2);
    const int fm = lane & 15, quad = lane >> 4;
    const int slq = kh * 4 + quad;
    int aoff[MI], boff[NJ];
    #pragma unroll
    for (int i = 0; i < MI; i++)
        aoff[i] = (wm + 16 * i + fm) * 128 + ((slq ^ (fm & 7)) * 16);
    #pragma unroll
    for (int j = 0; j < NJ; j++) {
        const int n = wn + 16 * j + fm;
        const int fb = (n ^ (n >> 2)) & 7;
        boff[j] = (TM + n) * 128 + ((slq ^ fb) * 16);
    }

    f32x4_t acc[MI][NJ] = {};
    bf16x4_t bufA[KPER], bufB[KPER];  // named buffers (no runtime idx)

    auto loadB = [&](int ks2, bf16x4_t (&dst)[KPER]) {
        const __bf16* q = bthr + (size_t)ks2 * bstep;
        #pragma unroll
        for (int j = 0; j < KPER; j++)
            dst[j] = *(const bf16x4_t*)(q + (size_t)j * ldb);
    };
    auto writeB = [&](int slot, const bf16x4_t (&src)[KPER]) {
        char* stg = (char*)smem + slot * (STG * 2);
        #pragma unroll
        for (int j = 0; j < 4; j++) {
            if constexpr (KPER == 4) {
                bf16x4_t u;
                u[0] = src[0][j]; u[1] = src[1][j];
                u[2] = src[2][j]; u[3] = src[3][j];
                *(bf16x4_t*)(stg + bwoff[j]) = u;
            } else {
                bf16x2_t u;
                u[0] = src[0][j]; u[1] = src[1][j];
                *(bf16x2_t*)(stg + bwoff[j]) = u;
            }
        }
    };

    // ---- prologue: vmem order entering body(0): B(1), A(0), B(2), A(1) ----
    loadB(0, bufA);
    loadB(1, bufB);
    #pragma unroll
    for (int i = 0; i < LA; i++) GLD16(srcs[i], smem + toff[i]);
    writeB(0, bufA);  // compiler-inserted wait covers only bufA's loads
    loadB(2, bufA);
    #pragma unroll
    for (int i = 0; i < LA; i++) GLD16(srcs[i] + 64, smem + STG + toff[i]);

    auto body = [&](int ks, bf16x4_t (&buf)[KPER]) {
        if (ks < NK - 2)
            asm volatile("s_waitcnt vmcnt(%0) lgkmcnt(0)\n\ts_barrier"
                         :: "i"(LB + LA) : "memory");
        else
            asm volatile("s_waitcnt vmcnt(0) lgkmcnt(0)\n\ts_barrier"
                         ::: "memory");
        if (ks + 1 < NK) writeB((ks + 1) % DEPTH, buf);
        if (ks + 3 < NK) loadB(ks + 3, buf);
        if (ks + 2 < NK) {
            #pragma unroll
            for (int i = 0; i < LA; i++)
                GLD16(srcs[i] + (size_t)(ks + 2) * 64,
                      smem + ((ks + 2) % DEPTH) * STG + toff[i]);
        }
        const char* st = (const char*)smem + (ks % DEPTH) * (STG * 2);
        bf16x8_t a[MI], b[NJ];
        #pragma unroll
        for (int i = 0; i < MI; i++) a[i] = *(const bf16x8_t*)(st + aoff[i]);
        #pragma unroll
        for (int j = 0; j < NJ; j++) b[j] = *(const bf16x8_t*)(st + boff[j]);
        __builtin_amdgcn_s_setprio(1);
        #pragma unroll
        for (int i = 0; i < MI; i++)
            #pragma unroll
            for (int j = 0; j < NJ; j++)
                acc[i][j] = __builtin_amdgcn_mfma_f32_16x16x32_bf16(
                    a[i], b[j], acc[i][j], 0, 0, 0);
        __builtin_amdgcn_s_setprio(0);
    };

    for (int ks = 0; ks < NK; ks += 2) {
        body(ks, bufB);
        body(ks + 1, bufA);
    }

    // ---- merge the two k-half accumulators through LDS (reuses stages) ----
    char* mrg = (char*)smem + wg * (MI * NJ * 64 * 16);
    __syncthreads();
    if (kh == 1) {
        #pragma unroll
        for (int i = 0; i < MI; i++)
            #pragma unroll
            for (int j = 0; j < NJ; j++)
                *(f32x4_t*)(mrg + (((i * NJ + j) * 64) + lane) * 16) = acc[i][j];
    }
    __syncthreads();
    if (kh == 1) return;
    #pragma unroll
    for (int i = 0; i < MI; i++)
        #pragma unroll
        for (int j = 0; j < NJ; j++) {
            const f32x4_t p =
                *(const f32x4_t*)(mrg + (((i * NJ + j) * 64) + lane) * 16);
            acc[i][j][0] += p[0]; acc[i][j][1] += p[1];
            acc[i][j][2] += p[2]; acc[i][j][3] += p[3];
        }

    // epilogue: C/D layout col=fm, row=quad*4+r  (waves 0..3 only)
    const float* bp = bias;
    if (QKV) {  // q|k|v segment select, uniform per block (TN=128-aligned)
        const int seg = n0 >> 11;
        bp = (seg == 0) ? bias : (seg == 1) ? biasB : biasC;
    }
    #pragma unroll
    for (int i = 0; i < MI; i++)
        #pragma unroll
        for (int j = 0; j < NJ; j++) {
            const int col = n0 + wn + 16 * j + fm;
            const float bcol = QKV ? bp[col & 2047] : bp[col];
            #pragma unroll
            for (int r = 0; r < 4; r++) {
                const int row = m0 + wm + 16 * i + quad * 4 + r;
                float val = acc[i][j][r] + bcol;
                if (RES) val += Res[(size_t)row * N + col];
                if (RELU) val = fmaxf(val, 0.0f);
                if (OUT_BF16)
                    ((__bf16*)Cout)[(size_t)row * N + col] = (__bf16)val;
                else
                    ((float*)Cout)[(size_t)row * N + col] = val;
            }
        }
}

// ---------------------------------------------------------------- Attention
// qkv bf16 [512, 6144] (q|k|v per row, each [H,DH]); o bf16 [512, 2048].
__global__ __launch_bounds__(128) void attn_kernel(
    const __bf16* __restrict__ qkv, __bf16* __restrict__ o) {
    const int bh = blockIdx.x;  // b*H + h
    const int b = bh >> 4, h = bh & 15;
    const size_t base = (size_t)b * (3 * DDIM) + h * DHEAD;
    const int tid = threadIdx.x;
    __shared__ float ks[DHEAD], vs[DHEAD];
    ks[tid] = (float)qkv[base + DDIM + tid];
    vs[tid] = (float)qkv[base + 2 * DDIM + tid];
    __syncthreads();
    const float a = (float)qkv[base + tid] * 0.08838834764831845f;  // /sqrt(128)
    float den = 0.0f, num = 0.0f;
    #pragma unroll 8
    for (int j = 0; j < DHEAD; j++) {
        float e = __expf(a * ks[j]);
        den += e;
        num += e * vs[j];
    }
    o[(size_t)b * DDIM + h * DHEAD + tid] = (__bf16)(num / den);
}

// ---------------------------------------------------------------- launch
extern "C" void kernel_launch(void* const* d_in, const int* in_sizes, int n_in,
                              void* d_out, int out_size, void* d_ws, size_t ws_size,
                              hipStream_t stream) {
    const float* x   = (const float*)d_in[0];
    const float* Wq  = (const float*)d_in[1];
    const float* bq  = (const float*)d_in[2];
    const float* Wk  = (const float*)d_in[3];
    const float* bk  = (const float*)d_in[4];
    const float* Wv  = (const float*)d_in[5];
    const float* bv  = (const float*)d_in[6];
    const float* Wo  = (const float*)d_in[7];
    const float* bo  = (const float*)d_in[8];
    const float* W1  = (const float*)d_in[9];
    const float* b1  = (const float*)d_in[10];
    const float* W2  = (const float*)d_in[11];
    const float* b2  = (const float*)d_in[12];
    const float* g1  = (const float*)d_in[13];
    const float* be1 = (const float*)d_in[14];
    const float* g2  = (const float*)d_in[15];
    const float* be2 = (const float*)d_in[16];
    float* out = (float*)d_out;

    // ---- workspace layout: casted weights (96 MB) + activations (~24 MB) ----
    char* base = (char*)d_ws;
    __bf16* wc   = (__bf16*)(base + 0);           // 48M bf16 = 96 MB
    __bf16* Wq_c = wc;                            // [16,2048,128]
    __bf16* Wk_c = wc + 4194304;
    __bf16* Wv_c = wc + 2 * 4194304;
    __bf16* Wo_c = wc + 3 * 4194304;              // [2048,2048]
    __bf16* W1_c = wc + 4 * 4194304;              // [2048,8192]
    __bf16* W2_c = wc + 8 * 4194304;              // [8192,2048]
    char* act = base + 100663296;
    __bf16* h   = (__bf16*)(act + 0);             // [512,2048]  2 MB
    __bf16* qkv = (__bf16*)(act + 2097152);       // [512,6144]  6 MB
    __bf16* ob  = (__bf16*)(act + 8388608);       // [512,2048]  2 MB
    float*  x1  = (float*)(act + 10485760);       // [512,2048]  4 MB
    __bf16* h2  = (__bf16*)(act + 14680064);      // [512,2048]  2 MB
    __bf16* t   = (__bf16*)(act + 16777216);      // [512,8192]  8 MB

    // 1. cast all weights to bf16 (identity layout) + h = LN(x)
    cast_ln_kernel<<<12800, 256, 0, stream>>>(Wq, Wk, Wv, Wo, W1, W2, x, g1,
                                              be1, wc, h);

    // 2. qkv = h @ [Wq|Wk|Wv] + [bq|bk|bv]
    gemm_af<64, 128, 1, 0, 0, 1><<<dim3(48, 8), 512, 0, stream>>>(
        h, DDIM, Wq_c, Wk_c, Wv_c, DHEAD, bq, bk, bv, nullptr, qkv, 3 * DDIM);

    // 3. per-sample outer-product attention
    attn_kernel<<<BROWS * HHEADS, 128, 0, stream>>>(qkv, ob);

    // 4. x1 = x + ob @ Wo + bo
    gemm_af<64, 64, 0, 0, 1, 0><<<dim3(32, 8), 512, 0, stream>>>(
        ob, DDIM, Wo_c, nullptr, nullptr, DDIM, bo, nullptr, nullptr, x,
        x1, DDIM);

    // 5. h2 = LN(x1)
    ln_kernel<<<BROWS, 256, 0, stream>>>(x1, g2, be2, h2);

    // 6. t = relu(h2 @ W1 + b1)
    gemm_af<64, 128, 1, 1, 0, 0><<<dim3(64, 8), 512, 0, stream>>>(
        h2, DDIM, W1_c, nullptr, nullptr, 4 * DDIM, b1, nullptr, nullptr,
        nullptr, t, 4 * DDIM);

    // 7. out = x1 + t @ W2 + b2   (no split-K: 256 blocks, fused epilogue)
    gemm_af<64, 64, 0, 0, 1, 0><<<dim3(32, 8), 512, 0, stream>>>(
        t, 4 * DDIM, W2_c, nullptr, nullptr, DDIM, b2, nullptr, nullptr, x1,
        out, DDIM);
}

// Round 9
// 332.130 us; speedup vs baseline: 1.1958x; 1.1958x over previous
//
#include <hip/hip_runtime.h>
#include <hip/hip_bf16.h>
#include <math.h>

// Block_46643344834722: pre-norm attention block, B=512 D=2048 H=16 DH=128.
// R12: no weight pre-pass at all (cast/transpose deleted -- measured flat
// ~85us at 2.4TB/s regardless of kernel shape).  GEMMs read fp32 weights
// [K,N] directly via R10's validated reg-staged B path, upsized to
// TM=TN=128 (halves B re-reads vs TM=64; GEMM is operand-stream-bound at
// ~16B/cy/CU per R10's 655MB/65us measurement).  8 waves = 4 wave-tiles
// (64x64) x 2 k-halves, DEPTH=3, single barrier/K-step, vmcnt(6) invariant.
// Split-K=4 for N=2048 gemms; Wo partial-reduce fused with LN2.
// 8 dispatches: ln1, qkv, attn, woP, reduce_ln, w1, w2P, reduce.

#define DDIM 2048
#define HHEADS 16
#define DHEAD 128
#define BROWS 512
#define LN_EPS 1e-5f

typedef __bf16 bf16x8_t __attribute__((ext_vector_type(8)));
typedef __bf16 bf16x4_t __attribute__((ext_vector_type(4)));
typedef float f32x4_t __attribute__((ext_vector_type(4)));

#define GLD16(gptr, lptr)                                                     \
    __builtin_amdgcn_global_load_lds(                                         \
        (const __attribute__((address_space(1))) void*)(gptr),                \
        (__attribute__((address_space(3))) void*)(lptr), 16, 0, 0)

// ---------------------------------------------------------------- LayerNorm
__global__ __launch_bounds__(256) void ln_kernel(const float* __restrict__ x,
                                                 const float* __restrict__ g,
                                                 const float* __restrict__ b,
                                                 __bf16* __restrict__ out) {
    const int row = blockIdx.x;
    const int tid = threadIdx.x;
    const float4* x4 = (const float4*)(x + (size_t)row * DDIM);
    float4 a = x4[2 * tid];
    float4 c = x4[2 * tid + 1];
    float s  = a.x + a.y + a.z + a.w + c.x + c.y + c.z + c.w;
    float s2 = a.x*a.x + a.y*a.y + a.z*a.z + a.w*a.w
             + c.x*c.x + c.y*c.y + c.z*c.z + c.w*c.w;
    #pragma unroll
    for (int off = 32; off > 0; off >>= 1) {
        s  += __shfl_down(s, off);
        s2 += __shfl_down(s2, off);
    }
    __shared__ float ps[4], ps2[4];
    __shared__ float mean_s, rstd_s;
    const int lane = tid & 63, w = tid >> 6;
    if (lane == 0) { ps[w] = s; ps2[w] = s2; }
    __syncthreads();
    if (tid == 0) {
        float S  = ps[0] + ps[1] + ps[2] + ps[3];
        float S2 = ps2[0] + ps2[1] + ps2[2] + ps2[3];
        float m  = S * (1.0f / DDIM);
        float var = S2 * (1.0f / DDIM) - m * m;
        mean_s = m;
        rstd_s = rsqrtf(var + LN_EPS);
    }
    __syncthreads();
    const float m = mean_s, r = rstd_s;
    const float4* g4 = (const float4*)g;
    const float4* b4 = (const float4*)b;
    float4 ga = g4[2 * tid], gb = g4[2 * tid + 1];
    float4 ba = b4[2 * tid], bb = b4[2 * tid + 1];
    bf16x8_t o;
    o[0] = (__bf16)((a.x - m) * r * ga.x + ba.x);
    o[1] = (__bf16)((a.y - m) * r * ga.y + ba.y);
    o[2] = (__bf16)((a.z - m) * r * ga.z + ba.z);
    o[3] = (__bf16)((a.w - m) * r * ga.w + ba.w);
    o[4] = (__bf16)((c.x - m) * r * gb.x + bb.x);
    o[5] = (__bf16)((c.y - m) * r * gb.y + bb.y);
    o[6] = (__bf16)((c.z - m) * r * gb.z + bb.z);
    o[7] = (__bf16)((c.w - m) * r * gb.w + bb.w);
    *(bf16x8_t*)(out + (size_t)row * DDIM + tid * 8) = o;
}

// ---------------------------------------------------------------- GEMM
// C[M,N] = A[M,K](bf16) @ B[K,N](fp32, cast in staging) + bias (+Res).
// TM=TN=128, 512 threads (8 waves: 4 wave-tiles 64x64 x 2 k-halves), BK=64.
// A: global_load_lds, source k-pre-swizzle (row&7 XOR).   LA=2 per wave.
// B: per-thread 4x4 fp32 patch -> bf16 -> transposed ds_write,
//    slot-XOR f(n)=(n^(n>>2))&7.                          LB=4 per thread.
// DEPTH=3, one barrier/K-step; issue order guarantees the barrier's
// vmcnt(LB+LA) covers A(ks) AND B(ks+1) (R10-validated invariant).
// QKV=1: B = per-head [2048,128] blocks of Wq|Wk|Wv (TN=128 = one head).
// SPLITZ>1: blockIdx.z takes K/SPLITZ slice, writes raw fp32 partials.
template <int SPLITZ, int OUT_BF16, int RELU, int RES, int QKV>
__global__ __launch_bounds__(512, 2) void gemm_af(
    const __bf16* __restrict__ A, int K,
    const float* __restrict__ Bq, const float* __restrict__ Bk,
    const float* __restrict__ Bv, int ldb,
    const float* __restrict__ bias, const float* __restrict__ biasB,
    const float* __restrict__ biasC, const float* __restrict__ Res,
    void* __restrict__ Cout, int N) {
    constexpr int TM = 128, TN = 128, DEPTH = 3;
    constexpr int STG = (TM + TN) * 64;  // bf16 elems per stage (BK=64)
    __shared__ __align__(16) __bf16 smem[DEPTH * STG];  // 96 KiB

    const int tid = threadIdx.x;
    const int w = tid >> 6, lane = tid & 63;

    // ---- XCD-aware block swizzle (gridDim.x % 8 == 0) ----
    const int gx = gridDim.x, gy = gridDim.y, gz = gridDim.z;
    int l = blockIdx.x + gx * (blockIdx.y + gy * blockIdx.z);
    const int xcd = l & 7;
    int i0 = l >> 3;
    const int by = i0 % gy; i0 /= gy;
    const int bz = i0 % gz; i0 /= gz;
    const int bx = xcd * (gx >> 3) + i0;

    const int m0 = by * TM, n0 = bx * TN;
    const int Kloc = K / SPLITZ;
    const int kb = bz * Kloc;
    const int NK = Kloc / 64;  // 32 (full) / 8 (Wo slice) -- even

    // ---- A staging (chunks of 8 rows x 64 k, one GLD16 per lane) ----
    constexpr int LA = TM / 64;  // 2
    const int srow = lane >> 3;
    const int sslot = (lane & 7) ^ srow;
    const __bf16* srcs[LA];
    int toff[LA];
    #pragma unroll
    for (int i = 0; i < LA; i++) {
        const int t = w + 8 * i;
        toff[i] = t * 512;
        srcs[i] = A + (size_t)(m0 + t * 8 + srow) * K + kb + sslot * 8;
    }

    // ---- B staging geometry (fp32 rows) ----
    constexpr int KPER = 4;        // k-rows per thread
    constexpr int LB = KPER;       // float4 loads per thread per stage
    constexpr int NPR = TN / 4;    // 32 threads per k-row-group
    const int np = tid & (NPR - 1);
    const int kp = tid / NPR;      // 0..15
    const int k0 = kp * KPER, n0t = np * 4;

    const float* bbase;
    if (QKV) {
        const int seg = n0 >> 11;
        const float* sel = (seg == 0) ? Bq : (seg == 1) ? Bk : Bv;
        bbase = sel + (size_t)((n0 & 2047) >> 7) * (DDIM * DHEAD);
    } else {
        bbase = Bq + n0;
    }
    const float* bthr = bbase + (size_t)(kb + k0) * ldb + n0t;
    const size_t bstep = (size_t)64 * ldb;

    int bwoff[4];
    {
        const int bslot = k0 >> 3, bhalf = (k0 & 7) * 2;
        #pragma unroll
        for (int j = 0; j < 4; j++) {
            const int n = n0t + j;
            const int fb = (n ^ (n >> 2)) & 7;
            bwoff[j] = (TM + n) * 128 + ((bslot ^ fb) * 16) + bhalf;
        }
    }

    // ---- wave tiling / fragment read offsets ----
    constexpr int MI = 4, NJ = 4;        // 64x64 wave-tile in 16-units
    const int wg = w & 3, kh = w >> 2;
    const int wm = (wg >> 1) * 64, wn = (wg & 1) * 64;
    const int fm = lane & 15, quad = lane >> 4;
    const int slq = kh * 4 + quad;
    int aoff[MI], boff[NJ];
    #pragma unroll
    for (int i = 0; i < MI; i++)
        aoff[i] = (wm + 16 * i + fm) * 128 + ((slq ^ (fm & 7)) * 16);
    #pragma unroll
    for (int j = 0; j < NJ; j++) {
        const int n = wn + 16 * j + fm;
        const int fb = (n ^ (n >> 2)) & 7;
        boff[j] = (TM + n) * 128 + ((slq ^ fb) * 16);
    }

    f32x4_t acc[MI][NJ] = {};
    f32x4_t bufA[KPER], bufB[KPER];  // named buffers (no runtime idx)

    auto loadB = [&](int ks2, f32x4_t (&dst)[KPER]) {
        const float* q = bthr + (size_t)ks2 * bstep;
        #pragma unroll
        for (int j = 0; j < KPER; j++)
            dst[j] = *(const f32x4_t*)(q + (size_t)j * ldb);
    };
    auto writeB = [&](int slot, const f32x4_t (&src)[KPER]) {
        char* stg = (char*)smem + slot * (STG * 2);
        #pragma unroll
        for (int j = 0; j < 4; j++) {
            bf16x4_t u;
            u[0] = (__bf16)src[0][j]; u[1] = (__bf16)src[1][j];
            u[2] = (__bf16)src[2][j]; u[3] = (__bf16)src[3][j];
            *(bf16x4_t*)(stg + bwoff[j]) = u;
        }
    };

    // ---- prologue: vmem order entering body(0): B(1), A(0), B(2), A(1) ----
    loadB(0, bufA);
    loadB(1, bufB);
    #pragma unroll
    for (int i = 0; i < LA; i++) GLD16(srcs[i], smem + toff[i]);
    writeB(0, bufA);  // compiler-inserted wait covers only bufA's loads
    loadB(2, bufA);
    #pragma unroll
    for (int i = 0; i < LA; i++) GLD16(srcs[i] + 64, smem + STG + toff[i]);

    // body(ks): barrier; writeB(ks+1) [covered by barrier's vmcnt];
    // loadB(ks+3) into SAME buffer; GLD16 A(ks+2); frag reads; MFMA.
    auto body = [&](int ks, f32x4_t (&buf)[KPER]) {
        if (ks < NK - 2)
            asm volatile("s_waitcnt vmcnt(%0) lgkmcnt(0)\n\ts_barrier"
                         :: "i"(LB + LA) : "memory");
        else
            asm volatile("s_waitcnt vmcnt(0) lgkmcnt(0)\n\ts_barrier"
                         ::: "memory");
        if (ks + 1 < NK) writeB((ks + 1) % DEPTH, buf);
        if (ks + 3 < NK) loadB(ks + 3, buf);
        if (ks + 2 < NK) {
            #pragma unroll
            for (int i = 0; i < LA; i++)
                GLD16(srcs[i] + (size_t)(ks + 2) * 64,
                      smem + ((ks + 2) % DEPTH) * STG + toff[i]);
        }
        const char* st = (const char*)smem + (ks % DEPTH) * (STG * 2);
        bf16x8_t a[MI], b[NJ];
        #pragma unroll
        for (int i = 0; i < MI; i++) a[i] = *(const bf16x8_t*)(st + aoff[i]);
        #pragma unroll
        for (int j = 0; j < NJ; j++) b[j] = *(const bf16x8_t*)(st + boff[j]);
        __builtin_amdgcn_s_setprio(1);
        #pragma unroll
        for (int i = 0; i < MI; i++)
            #pragma unroll
            for (int j = 0; j < NJ; j++)
                acc[i][j] = __builtin_amdgcn_mfma_f32_16x16x32_bf16(
                    a[i], b[j], acc[i][j], 0, 0, 0);
        __builtin_amdgcn_s_setprio(0);
    };

    for (int ks = 0; ks < NK; ks += 2) {
        body(ks, bufB);
        body(ks + 1, bufA);
    }

    // ---- merge the two k-half accumulators through LDS (reuses stages) ----
    char* mrg = (char*)smem + wg * 16384;
    __syncthreads();
    if (kh == 1) {
        #pragma unroll
        for (int i = 0; i < MI; i++)
            #pragma unroll
            for (int j = 0; j < NJ; j++)
                *(f32x4_t*)(mrg + (((i * NJ + j) * 64) + lane) * 16) = acc[i][j];
    }
    __syncthreads();
    if (kh == 1) return;
    #pragma unroll
    for (int i = 0; i < MI; i++)
        #pragma unroll
        for (int j = 0; j < NJ; j++) {
            const f32x4_t p =
                *(const f32x4_t*)(mrg + (((i * NJ + j) * 64) + lane) * 16);
            acc[i][j][0] += p[0]; acc[i][j][1] += p[1];
            acc[i][j][2] += p[2]; acc[i][j][3] += p[3];
        }

    // epilogue: C/D layout col=fm, row=quad*4+r  (waves 0..3 only)
    if (SPLITZ > 1) {
        float* P = (float*)Cout + (size_t)bz * (gy * TM) * N;
        #pragma unroll
        for (int i = 0; i < MI; i++)
            #pragma unroll
            for (int j = 0; j < NJ; j++) {
                const int col = n0 + wn + 16 * j + fm;
                #pragma unroll
                for (int r = 0; r < 4; r++) {
                    const int row = m0 + wm + 16 * i + quad * 4 + r;
                    P[(size_t)row * N + col] = acc[i][j][r];
                }
            }
    } else {
        const float* bp = bias;
        if (QKV) {  // seg uniform per block (TN=128-aligned)
            const int seg = n0 >> 11;
            bp = (seg == 0) ? bias : (seg == 1) ? biasB : biasC;
        }
        #pragma unroll
        for (int i = 0; i < MI; i++)
            #pragma unroll
            for (int j = 0; j < NJ; j++) {
                const int col = n0 + wn + 16 * j + fm;
                const float bcol = QKV ? bp[col & 2047] : bp[col];
                #pragma unroll
                for (int r = 0; r < 4; r++) {
                    const int row = m0 + wm + 16 * i + quad * 4 + r;
                    float val = acc[i][j][r] + bcol;
                    if (RES) val += Res[(size_t)row * N + col];
                    if (RELU) val = fmaxf(val, 0.0f);
                    if (OUT_BF16)
                        ((__bf16*)Cout)[(size_t)row * N + col] = (__bf16)val;
                    else
                        ((float*)Cout)[(size_t)row * N + col] = val;
                }
            }
    }
}

// ---------------------------------------------------------------- split-K sum
// out[512,2048] = Res + bias(per-col) + sum_s part[s]
template <int NS>
__global__ __launch_bounds__(256) void reduce_splitk(
    const float* __restrict__ part, const float* __restrict__ Res,
    const float* __restrict__ bias, float* __restrict__ out) {
    const int idx = blockIdx.x * 256 + threadIdx.x;  // 0..262143 float4s
    const float4 b4 = ((const float4*)bias)[idx & 511];
    float4 r = ((const float4*)Res)[idx];
    #pragma unroll
    for (int s = 0; s < NS; s++) {
        const float4 p = ((const float4*)part)[(size_t)s * 262144 + idx];
        r.x += p.x; r.y += p.y; r.z += p.z; r.w += p.w;
    }
    r.x += b4.x; r.y += b4.y; r.z += b4.z; r.w += b4.w;
    ((float4*)out)[idx] = r;
}

// ---------------------------------------------------------------- reduce+LN
// x1[row] = x[row] + bo + sum_s part[s][row];  h2[row] = LN(x1[row])*g+be
template <int NS>
__global__ __launch_bounds__(256) void reduce_ln_kernel(
    const float* __restrict__ part, const float* __restrict__ x,
    const float* __restrict__ bo, const float* __restrict__ g,
    const float* __restrict__ be, float* __restrict__ x1,
    __bf16* __restrict__ h2) {
    const int row = blockIdx.x;
    const int tid = threadIdx.x;
    const size_t rbase = (size_t)row * DDIM;
    float v[8];
    #pragma unroll
    for (int p = 0; p < 2; p++) {
        const int c = tid * 8 + p * 4;
        float4 r = *(const float4*)(x + rbase + c);
        const float4 b4 = *(const float4*)(bo + c);
        r.x += b4.x; r.y += b4.y; r.z += b4.z; r.w += b4.w;
        #pragma unroll
        for (int s = 0; s < NS; s++) {
            const float4 q =
                *(const float4*)(part + (size_t)s * BROWS * DDIM + rbase + c);
            r.x += q.x; r.y += q.y; r.z += q.z; r.w += q.w;
        }
        *(float4*)(x1 + rbase + c) = r;
        v[p * 4 + 0] = r.x; v[p * 4 + 1] = r.y;
        v[p * 4 + 2] = r.z; v[p * 4 + 3] = r.w;
    }
    float s = 0.f, s2 = 0.f;
    #pragma unroll
    for (int i = 0; i < 8; i++) { s += v[i]; s2 += v[i] * v[i]; }
    #pragma unroll
    for (int off = 32; off > 0; off >>= 1) {
        s  += __shfl_down(s, off);
        s2 += __shfl_down(s2, off);
    }
    __shared__ float ps[4], ps2[4];
    __shared__ float mean_s, rstd_s;
    const int lane = tid & 63, wv = tid >> 6;
    if (lane == 0) { ps[wv] = s; ps2[wv] = s2; }
    __syncthreads();
    if (tid == 0) {
        float S  = ps[0] + ps[1] + ps[2] + ps[3];
        float S2 = ps2[0] + ps2[1] + ps2[2] + ps2[3];
        float m  = S * (1.0f / DDIM);
        float var = S2 * (1.0f / DDIM) - m * m;
        mean_s = m;
        rstd_s = rsqrtf(var + LN_EPS);
    }
    __syncthreads();
    const float m = mean_s, r = rstd_s;
    const float4* g4 = (const float4*)g;
    const float4* b4 = (const float4*)be;
    float4 ga = g4[2 * tid], gb = g4[2 * tid + 1];
    float4 ba = b4[2 * tid], bb = b4[2 * tid + 1];
    bf16x8_t o;
    o[0] = (__bf16)((v[0] - m) * r * ga.x + ba.x);
    o[1] = (__bf16)((v[1] - m) * r * ga.y + ba.y);
    o[2] = (__bf16)((v[2] - m) * r * ga.z + ba.z);
    o[3] = (__bf16)((v[3] - m) * r * ga.w + ba.w);
    o[4] = (__bf16)((v[4] - m) * r * gb.x + bb.x);
    o[5] = (__bf16)((v[5] - m) * r * gb.y + bb.y);
    o[6] = (__bf16)((v[6] - m) * r * gb.z + bb.z);
    o[7] = (__bf16)((v[7] - m) * r * gb.w + bb.w);
    *(bf16x8_t*)(h2 + rbase + tid * 8) = o;
}

// ---------------------------------------------------------------- Attention
// qkv bf16 [512, 6144] (q|k|v per row, each [H,DH]); o bf16 [512, 2048].
__global__ __launch_bounds__(128) void attn_kernel(
    const __bf16* __restrict__ qkv, __bf16* __restrict__ o) {
    const int bh = blockIdx.x;  // b*H + h
    const int b = bh >> 4, h = bh & 15;
    const size_t base = (size_t)b * (3 * DDIM) + h * DHEAD;
    const int tid = threadIdx.x;
    __shared__ float ks[DHEAD], vs[DHEAD];
    ks[tid] = (float)qkv[base + DDIM + tid];
    vs[tid] = (float)qkv[base + 2 * DDIM + tid];
    __syncthreads();
    const float a = (float)qkv[base + tid] * 0.08838834764831845f;  // /sqrt(128)
    float den = 0.0f, num = 0.0f;
    #pragma unroll 8
    for (int j = 0; j < DHEAD; j++) {
        float e = __expf(a * ks[j]);
        den += e;
        num += e * vs[j];
    }
    o[(size_t)b * DDIM + h * DHEAD + tid] = (__bf16)(num / den);
}

// ---------------------------------------------------------------- launch
extern "C" void kernel_launch(void* const* d_in, const int* in_sizes, int n_in,
                              void* d_out, int out_size, void* d_ws, size_t ws_size,
                              hipStream_t stream) {
    const float* x   = (const float*)d_in[0];
    const float* Wq  = (const float*)d_in[1];
    const float* bq  = (const float*)d_in[2];
    const float* Wk  = (const float*)d_in[3];
    const float* bk  = (const float*)d_in[4];
    const float* Wv  = (const float*)d_in[5];
    const float* bv  = (const float*)d_in[6];
    const float* Wo  = (const float*)d_in[7];
    const float* bo  = (const float*)d_in[8];
    const float* W1  = (const float*)d_in[9];
    const float* b1  = (const float*)d_in[10];
    const float* W2  = (const float*)d_in[11];
    const float* b2  = (const float*)d_in[12];
    const float* g1  = (const float*)d_in[13];
    const float* be1 = (const float*)d_in[14];
    const float* g2  = (const float*)d_in[15];
    const float* be2 = (const float*)d_in[16];
    float* out = (float*)d_out;

    // ---- workspace: activations + partials only (~56 MB) ----
    char* act = (char*)d_ws;
    __bf16* h   = (__bf16*)(act + 0);             // [512,2048]  2 MB
    __bf16* qkv = (__bf16*)(act + 2097152);       // [512,6144]  6 MB
    __bf16* ob  = (__bf16*)(act + 8388608);       // [512,2048]  2 MB
    float*  x1  = (float*)(act + 10485760);       // [512,2048]  4 MB
    __bf16* h2  = (__bf16*)(act + 14680064);      // [512,2048]  2 MB
    __bf16* t   = (__bf16*)(act + 16777216);      // [512,8192]  8 MB
    float*  woP = (float*)(act + 25165824);       // [4][512,2048] 16 MB
    float*  w2P = (float*)(act + 41943040);       // [4][512,2048] 16 MB

    // 1. h = LN(x)
    ln_kernel<<<BROWS, 256, 0, stream>>>(x, g1, be1, h);

    // 2. qkv = h @ [Wq|Wk|Wv] + [bq|bk|bv]   (fp32 weights direct)
    gemm_af<1, 1, 0, 0, 1><<<dim3(48, 4), 512, 0, stream>>>(
        h, DDIM, Wq, Wk, Wv, DHEAD, bq, bk, bv, nullptr, qkv, 3 * DDIM);

    // 3. per-sample outer-product attention
    attn_kernel<<<BROWS * HHEADS, 128, 0, stream>>>(qkv, ob);

    // 4. woP = ob @ Wo partials (split-K=4, 256 blocks)
    gemm_af<4, 0, 0, 0, 0><<<dim3(16, 4, 4), 512, 0, stream>>>(
        ob, DDIM, Wo, nullptr, nullptr, DDIM, nullptr, nullptr, nullptr,
        nullptr, woP, DDIM);

    // 5. x1 = x + sum(woP) + bo;  h2 = LN(x1)
    reduce_ln_kernel<4><<<BROWS, 256, 0, stream>>>(woP, x, bo, g2, be2, x1, h2);

    // 6. t = relu(h2 @ W1 + b1)
    gemm_af<1, 1, 1, 0, 0><<<dim3(64, 4), 512, 0, stream>>>(
        h2, DDIM, W1, nullptr, nullptr, 4 * DDIM, b1, nullptr, nullptr,
        nullptr, t, 4 * DDIM);

    // 7. w2P = t @ W2 partials (split-K=4, 256 blocks)
    gemm_af<4, 0, 0, 0, 0><<<dim3(16, 4, 4), 512, 0, stream>>>(
        t, 4 * DDIM, W2, nullptr, nullptr, DDIM, nullptr, nullptr, nullptr,
        nullptr, w2P, DDIM);

    // 8. out = x1 + sum(w2P) + b2
    reduce_splitk<4><<<1024, 256, 0, stream>>>(w2P, x1, b2, out);
}